// Round 3
// baseline (253.285 us; speedup 1.0000x reference)
//
#include <hip/hip_runtime.h>

#define T_STEPS 2000
#define BATCH   2048
#define TPAD    2048   // padded time stride for ws layout [b][t]
#define TT      16     // t-outputs per thread in conv pass (keeps VGPR < 128, no spill)

// ---------------- Pass 1: currents convolution ----------------
// x''[t,b] = (sum_j a[j]*c[t-63+j, b] - b_act) / max_current, written to xt[b][t]
__global__ __launch_bounds__(256) void conv_kernel(
    const float* __restrict__ currents, const float* __restrict__ a,
    const float* __restrict__ b_act, const float* __restrict__ max_current,
    float* __restrict__ xt)
{
    __shared__ float sa[64];
    int tid = threadIdx.x;
    if (tid < 64) sa[tid] = a[tid];
    __syncthreads();

    int b  = blockIdx.y * 256 + tid;
    int t0 = blockIdx.x * TT;

    float w[TT + 63];
#pragma unroll
    for (int k = 0; k < TT + 63; ++k) {
        int tau = t0 - 63 + k;
        w[k] = (tau >= 0 && tau < T_STEPS) ? currents[(long)tau * BATCH + b] : 0.0f;
    }

    float acc[TT];
#pragma unroll
    for (int i = 0; i < TT; ++i) acc[i] = 0.0f;

#pragma unroll
    for (int j = 0; j < 64; ++j) {
        float aj = sa[j];
#pragma unroll
        for (int i = 0; i < TT; ++i)
            acc[i] = fmaf(aj, w[i + j], acc[i]);
    }

    float ba     = b_act[0];
    float inv_mc = 1.0f / max_current[0];
#pragma unroll
    for (int i = 0; i < TT; ++i) {
        int t = t0 + i;
        if (t < T_STEPS) xt[(long)b * TPAD + t] = (acc[i] - ba) * inv_mc;
    }
}

// ---------------- Pass 2: sequential recurrence, one wave per batch --------
// Scatter-ring: lane L owns future step s with s == L (mod 64). acc holds
// x''[s] + sum of gamma-weighted f contributions so far; at step t, lane t&63
// is complete -> readlane (immediate lane index after full unroll).
// Coefficients preloaded to 64 registers: cf[s] = g2[lane+63-s] — no LDS in
// the hot loop. xn (next chunk's x'') prefetched one chunk ahead.
__global__ __launch_bounds__(256) void recur_kernel(
    const float* __restrict__ xt, const float* __restrict__ b_lag,
    const float* __restrict__ poly_coeff, const float* __restrict__ max_current,
    const float* __restrict__ max_firing_rate, float* __restrict__ out)
{
    __shared__ float g2[128];  // gamma duplicated: g2[j] = gamma[j & 63]
    int tid = threadIdx.x;
    float mc    = max_current[0];
    float scale = 1000.0f / mc;
    if (tid < 128) {
        int i = tid & 63;
        g2[tid] = scale * b_lag[63 - i];   // gamma[i] = scale*b_lag[63-i]
    }
    __syncthreads();

    int lane = tid & 63;
    int wid  = tid >> 6;
    int b    = blockIdx.x * 4 + wid;

    // tanh(p) = 1 - 2/(exp2(K2*p)+1); fold K2=2*log2(e) into squared coeffs
    const float K2 = 2.8853900817779268f;
    float c0 = poly_coeff[0], c1 = poly_coeff[1], c2 = poly_coeff[2], c3 = poly_coeff[3];
    float k0 = K2 * c0 * c0, k1 = K2 * c1 * c1, k2 = K2 * c2 * c2, k3 = K2 * c3 * c3;
    float M  = max_firing_rate[0];
    float m2 = -2.0f * M;

    // per-lane coefficient schedule: cf[s] = gamma[(lane-1-s) & 63]
    float cf[64];
#pragma unroll
    for (int s = 0; s < 64; ++s) cf[s] = g2[lane + 63 - s];

    const float* xrow = xt + (long)b * TPAD;
    float acc = xrow[lane];        // chunk 0: x''[lane], zero history
    float xn  = xrow[64 + lane];   // chunk 0 ring-reset values x''[64+lane]
    float fv  = 0.0f;
    float* outcol = out + b;

    auto step = [&](int s, float xcur) {
        float u = __builtin_bit_cast(float,
                    __builtin_amdgcn_readlane(__builtin_bit_cast(int, acc), s));
        float u2 = u * u;
        float a1 = fmaf(u, k1, k0);
        float a2 = fmaf(u, k3, k2);
        float p  = fminf(fmaf(u2, a2, a1), 126.0f);     // exp2 overflow guard
        float e  = __builtin_amdgcn_exp2f(p);
        float r  = __builtin_amdgcn_rcpf(e + 1.0f);
        float f  = fmaxf(fmaf(m2, r, M), 0.0f);         // relu(M*tanh), overflow-free
        bool own = (lane == s);
        acc = fmaf(cf[s], f, own ? xcur : acc);         // cndmask off critical path
        fv  = own ? f : fv;
    };

    // 31 full chunks of 64 steps (t = 0 .. 1983)
    for (int chunk = 0; chunk < 31; ++chunk) {
        int t0  = chunk * 64;
        int tn2 = t0 + 128 + lane;                      // prefetch next chunk's resets
        float xn_next = (tn2 < T_STEPS) ? xrow[tn2] : 0.0f;
#pragma unroll
        for (int s = 0; s < 64; ++s) step(s, xn);
        outcol[(long)(t0 + lane) * BATCH] = fv;
        xn = xn_next;
    }
    // tail: 16 steps (t = 1984 .. 1999)
#pragma unroll
    for (int s = 0; s < 16; ++s) step(s, 0.0f);
    if (lane < 16) outcol[(long)(1984 + lane) * BATCH] = fv;
}

extern "C" void kernel_launch(void* const* d_in, const int* in_sizes, int n_in,
                              void* d_out, int out_size, void* d_ws, size_t ws_size,
                              hipStream_t stream) {
    const float* currents   = (const float*)d_in[0];
    const float* a          = (const float*)d_in[1];
    const float* b_lag      = (const float*)d_in[2];
    const float* poly_coeff = (const float*)d_in[3];
    const float* b_act      = (const float*)d_in[4];
    const float* mc         = (const float*)d_in[5];
    const float* mfr        = (const float*)d_in[6];
    float* out = (float*)d_out;
    float* xt  = (float*)d_ws;   // needs BATCH*TPAD*4 = 16.78 MB

    conv_kernel<<<dim3(T_STEPS / TT, BATCH / 256), 256, 0, stream>>>(
        currents, a, b_act, mc, xt);
    recur_kernel<<<BATCH / 4, 256, 0, stream>>>(
        xt, b_lag, poly_coeff, mc, mfr, out);
}

// Round 5
// 211.219 us; speedup vs baseline: 1.1992x; 1.1992x over previous
//
#include <hip/hip_runtime.h>

#define T_STEPS 2000
#define BATCH   2048

// Fully fused: conv + recurrence in one rotating-ring kernel, one wave per batch.
//
// Ring invariant (entering global step t): lane L holds
//   R_L = cba + sum_{tau<=t-1} (a[63-(t+L-tau)]/mc) * c_tau        (x part, partial)
//       +       sum_{tau<=t-1} gamma-weighted f_tau                (y part, partial)
// where cba = -b_act/mc. Per step t:
//   1. R += af * c_t          af[L] = a[63-L]/mc   (lane 0 now = u_t complete)
//   2. u = readlane(R, 0);  f_t = relu(M * tanh(poly(u)))
//   3. rotate R left one lane (DPP wave_rol:1: dst[L] = src[L+1], wrap)
//   4. lane 63 <- cba (fresh slot for target t+64)
//   5. R += gam * f_t         gam[L] = (1000/mc) * b_lag[63-L]  (fixed per lane)
// No LDS, no workspace, no second kernel. currents read once (16 MB).
__global__ __launch_bounds__(256) void fused_kernel(
    const float* __restrict__ currents, const float* __restrict__ a,
    const float* __restrict__ b_lag, const float* __restrict__ poly_coeff,
    const float* __restrict__ b_act, const float* __restrict__ max_current,
    const float* __restrict__ max_firing_rate, float* __restrict__ out)
{
    int tid  = threadIdx.x;
    int lane = tid & 63;
    int wid  = tid >> 6;
    int b    = blockIdx.x * 4 + wid;

    float inv = 1.0f / max_current[0];
    float cba = -b_act[0] * inv;
    float af  = a[63 - lane] * inv;                 // fixed per-lane conv tap
    float gam = (1000.0f * inv) * b_lag[63 - lane]; // fixed per-lane feedback tap

    // tanh(p) = 1 - 2/(exp2(K2*p)+1); K2 = 2*log2(e) folded into squared coeffs.
    // Overflow-safe: p=+inf -> e=inf, r=0, f=M; p=-inf -> e=0, r=1, f=relu(-M)=0.
    const float K2 = 2.8853900817779268f;
    float c0 = poly_coeff[0], c1 = poly_coeff[1], c2 = poly_coeff[2], c3 = poly_coeff[3];
    float k0 = K2 * c0 * c0, k1 = K2 * c1 * c1, k2 = K2 * c2 * c2, k3 = K2 * c3 * c3;
    float M  = max_firing_rate[0];
    float m2 = -2.0f * M;

    auto bcast = [](float v, int l) {
        return __builtin_bit_cast(float,
            __builtin_amdgcn_readlane(__builtin_bit_cast(int, v), l));
    };
    auto rotl1 = [](float v) {   // dst[L] = src[(L+1) & 63]
        int i = __builtin_bit_cast(int, v);
        return __builtin_bit_cast(float,
            __builtin_amdgcn_update_dpp(i, i, 0x134, 0xf, 0xf, false));
    };

    const float* ccol   = currents + b;
    float*       outcol = out + b;

    float R  = cba;                          // all slots born with the bias
    float cv = ccol[(long)lane * BATCH];     // c[lane] for chunk 0
    float fv = 0.0f;

    auto step = [&](int s) {
        float c = bcast(cv, s);                       // c_t (wave-uniform)
        R = fmaf(af, c, R);                           // complete lane 0 -> u_t
        float u = bcast(R, 0);
        float u2 = u * u;                             // Estrin, depth 2
        float a1 = fmaf(u, k1, k0);
        float a2 = fmaf(u, k3, k2);
        float p  = fmaf(u2, a2, a1);
        float e  = __builtin_amdgcn_exp2f(p);
        float r  = __builtin_amdgcn_rcpf(e + 1.0f);
        float f  = fmaxf(fmaf(m2, r, M), 0.0f);       // relu(M*tanh), overflow-free
        float Rr = rotl1(R);                          // slots shift down one lane
        Rr = (lane == 63) ? cba : Rr;                 // fresh slot for t+64
        R  = fmaf(gam, f, Rr);
        fv = (lane == s) ? f : fv;                    // stash f[t0+s] in lane s
    };

    // 31 full chunks of 64 steps (t = 0 .. 1983)
    for (int chunk = 0; chunk < 31; ++chunk) {
        int t0 = chunk * 64;
        int tp = t0 + 64 + lane;                      // prefetch next chunk's currents
        float cv_next = (tp < T_STEPS) ? ccol[(long)tp * BATCH] : 0.0f;
#pragma unroll
        for (int s = 0; s < 64; ++s) step(s);
        outcol[(long)(t0 + lane) * BATCH] = fv;
        cv = cv_next;
    }
    // tail: 16 steps (t = 1984 .. 1999)
#pragma unroll
    for (int s = 0; s < 16; ++s) step(s);
    if (lane < 16) outcol[(long)(1984 + lane) * BATCH] = fv;
}

extern "C" void kernel_launch(void* const* d_in, const int* in_sizes, int n_in,
                              void* d_out, int out_size, void* d_ws, size_t ws_size,
                              hipStream_t stream) {
    const float* currents   = (const float*)d_in[0];
    const float* a          = (const float*)d_in[1];
    const float* b_lag      = (const float*)d_in[2];
    const float* poly_coeff = (const float*)d_in[3];
    const float* b_act      = (const float*)d_in[4];
    const float* mc         = (const float*)d_in[5];
    const float* mfr        = (const float*)d_in[6];
    float* out = (float*)d_out;

    fused_kernel<<<BATCH / 4, 256, 0, stream>>>(
        currents, a, b_lag, poly_coeff, b_act, mc, mfr, out);
}